// Round 8
// baseline (2902.878 us; speedup 1.0000x reference)
//
#include <hip/hip_runtime.h>

typedef __attribute__((ext_vector_type(4))) float f32x4;
typedef __attribute__((ext_vector_type(8))) short bf16x8;

#define DEV __device__ __forceinline__

DEV float b2f(ushort u) { return __uint_as_float(((uint)u) << 16); }
DEV ushort f2b(float f) {
    uint u = __float_as_uint(f);
    return (ushort)((u + 0x7fffu + ((u >> 16) & 1u)) >> 16);  // RNE
}
DEV float fsig(float x) {
    return __builtin_amdgcn_rcpf(1.f + __builtin_amdgcn_exp2f(-1.4426950408889634f * x));
}
DEV float ftanh(float x) {
    return 1.f - 2.f * __builtin_amdgcn_rcpf(__builtin_amdgcn_exp2f(2.885390081777927f * x) + 1.f);
}
DEV void gload_lds16(const void* g, void* l) {
    __builtin_amdgcn_global_load_lds(
        (const __attribute__((address_space(1))) void*)g,
        (__attribute__((address_space(3))) void*)l, 16, 0, 0);
}
// staging load, SC0 only: bypass L1, may hit local (XCD) L2
DEV void gload_lds16_l2(const void* g, void* l) {
    __builtin_amdgcn_global_load_lds(
        (const __attribute__((address_space(1))) void*)g,
        (__attribute__((address_space(3))) void*)l, 16, 0, 1);
}
DEV void store_sc_u32(uint* p, uint v) {
    asm volatile("global_store_dword %0, %1, off sc0 sc1" :: "v"(p), "v"(v) : "memory");
}
DEV uint load_sc_u32(const uint* p) {
    uint v;
    asm volatile("global_load_dword %0, %1, off sc0 sc1\n\ts_waitcnt vmcnt(0)"
                 : "=v"(v) : "v"(p) : "memory");
    return v;
}

// ---------------- f32 -> bf16 weight conversion ----------------
__global__ void f2b_kernel(const float* __restrict__ s, ushort* __restrict__ d, int n) {
    int i = blockIdx.x * 256 + threadIdx.x;
    if (i < n) d[i] = f2b(s[i]);
}

// ---------------- embedding gather -> x0 [S][B][E] bf16 ----------------
__global__ void embed_kernel(const int* __restrict__ tok, const float* __restrict__ emb,
                             ushort* __restrict__ x0) {
    int row = blockIdx.x;
    int t = row >> 9, b = row & 511;
    int tk = tok[b * 128 + t];
    x0[(size_t)row * 256 + threadIdx.x] = f2b(emb[(size_t)tk * 256 + threadIdx.x]);
}

// ---------------- bf16 NT GEMM (m97-style): C[m][n] = A[m][:]·Bw[n][:] + bias ----------------
__global__ __launch_bounds__(256) void gemm_bias_kernel(
    const ushort* __restrict__ A, const ushort* __restrict__ Bw,
    const float* __restrict__ bias0, const float* __restrict__ bias1,
    ushort* __restrict__ C, int M, int N, int K) {
    __shared__ ushort la[128 * 32];
    __shared__ ushort lb[128 * 32];
    const int tid = threadIdx.x;
    const int wave = tid >> 6, lane = tid & 63;
    const int ntn = N >> 7;
    const int tm = blockIdx.x / ntn, tn = blockIdx.x % ntn;
    const int m0 = tm << 7, n0 = tn << 7;
    const int wm = (wave >> 1) * 64, wn = (wave & 1) * 64;
    f32x4 acc[4][4] = {};
    const int nks = K >> 5;
    const int srow = tid >> 2, scol = (tid & 3) * 8;
    for (int ks = 0; ks < nks; ++ks) {
        const int k0 = ks << 5;
#pragma unroll
        for (int r = 0; r < 2; ++r) {
            gload_lds16(A + (size_t)(m0 + r * 64 + srow) * K + k0 + scol, &la[r * 2048 + wave * 512]);
            gload_lds16(Bw + (size_t)(n0 + r * 64 + srow) * K + k0 + scol, &lb[r * 2048 + wave * 512]);
        }
        __syncthreads();
        bf16x8 af[4], bfr[4];
#pragma unroll
        for (int i = 0; i < 4; ++i)
            af[i] = *(const bf16x8*)&la[(wm + i * 16 + (lane & 15)) * 32 + (lane >> 4) * 8];
#pragma unroll
        for (int i = 0; i < 4; ++i)
            bfr[i] = *(const bf16x8*)&lb[(wn + i * 16 + (lane & 15)) * 32 + (lane >> 4) * 8];
#pragma unroll
        for (int mi = 0; mi < 4; ++mi)
#pragma unroll
            for (int ni = 0; ni < 4; ++ni)
                acc[mi][ni] = __builtin_amdgcn_mfma_f32_16x16x32_bf16(af[mi], bfr[ni], acc[mi][ni], 0, 0, 0);
        __syncthreads();
    }
#pragma unroll
    for (int mi = 0; mi < 4; ++mi) {
        int row = m0 + wm + mi * 16 + ((lane >> 4) << 2);
#pragma unroll
        for (int j = 0; j < 4; ++j) {
#pragma unroll
            for (int ni = 0; ni < 4; ++ni) {
                int col = n0 + wn + ni * 16 + (lane & 15);
                C[(size_t)(row + j) * N + col] = f2b(acc[mi][ni][j] + bias0[col] + bias1[col]);
            }
        }
    }
}

// ---------------- persistent LSTM chunk: 32 timesteps, device-scope flag barrier ----------------
// grid 256 = 8 batch-groups (grp = bid&7, XCD-local staging) x 32 h-slices.
// Whh in regs: 2x2 wave tiling (row-halves x gate-pairs), Bfr[2][16] = 128 VGPR.
// hp staged in MFMA-FRAGMENT ORDER: chunk c = ks*4+mi is a 1KB run; lane l's 16B at
// c*1024 + l*16 holds h[b0 + mi*16 + (l&15)][ks*32 + (l>>4)*8]. Per-lane gather is on the
// GLOBAL side (global_load_lds per-lane src); LDS stays linear -> ds_read_b128 conflict-free.
__global__ __launch_bounds__(256) void lstm_chunk_kernel(
    const ushort* __restrict__ xpj,   // [32][512][2048] bf16 (x-projections incl. biases)
    const ushort* __restrict__ Whh,   // [2048][512] bf16
    ushort* __restrict__ hs,          // [128][512][512] bf16 (layer history)
    float* __restrict__ cstate,       // [512][512] f32
    float* __restrict__ hT, float* __restrict__ cT,
    uint* __restrict__ bar,           // this launch: 8 groups x 32 slices x 16 uints (zeroed)
    int t0) {
    __shared__ ushort hp[64 * 512];    // 64KB, fragment-ordered chunks
    __shared__ float gbuf[4][64][18];  // padded: 18 keeps float2 align, breaks 4-way write conflict
    const int tid = threadIdx.x;
    const int w = tid >> 6, lane = tid & 63;
    const int l15 = lane & 15, lh = lane >> 4;
    const int wr = w >> 1, wc = w & 1;  // wave tile: rows 2wr..2wr+1 (x16), gates 2wc..2wc+1
    const int grp = blockIdx.x & 7;    // XCD-local group
    const int hsl = blockIdx.x >> 3;   // h-slice 0..31
    const int b0 = grp << 6, h0 = hsl << 4;
    uint* gflags = bar + grp * 512;
    uint* myflag = gflags + hsl * 16;

    // one-time acquire: drop stale L2 lines from previous dispatches/replays
    __threadfence();

    // B-frags: 2 gates x 16 ks (128 VGPR)
    bf16x8 Bfr[2][16];
#pragma unroll
    for (int gg = 0; gg < 2; ++gg) {
        const ushort* wb = Whh + (size_t)((2 * wc + gg) * 512 + h0 + l15) * 512 + lh * 8;
#pragma unroll
        for (int ks = 0; ks < 16; ++ks) Bfr[gg][ks] = *(const bf16x8*)(wb + ks * 32);
    }

    // c-state registers (2 adjacent h per slot pair)
    float creg[4];
#pragma unroll
    for (int i = 0; i < 2; ++i) {
        const int e2 = i * 512 + tid * 2;
        const size_t ci = (size_t)(b0 + (e2 >> 4)) * 512 + h0 + (e2 & 15);
        if (t0 > 0) {
            float2 cv = *(const float2*)&cstate[ci];
            creg[2 * i] = cv.x; creg[2 * i + 1] = cv.y;
        } else {
            creg[2 * i] = 0.f; creg[2 * i + 1] = 0.f;
        }
    }

    for (int tt = 0; tt < 32; ++tt) {
        const int t = t0 + tt;
        // prefetch this step's xpj gate pairs (hides under flag spin)
        uint xq[2][4];
        const ushort* xt = xpj + (size_t)tt * 1048576;
#pragma unroll
        for (int i = 0; i < 2; ++i) {
            const int e2 = i * 512 + tid * 2;
            const uint* xb = (const uint*)(xt + (size_t)(b0 + (e2 >> 4)) * 2048 + h0 + (e2 & 15));
            xq[i][0] = xb[0]; xq[i][1] = xb[256]; xq[i][2] = xb[512]; xq[i][3] = xb[768];
        }
        // wait for all 32 slice-blocks of this group to have produced h[t-1]
        if (tt > 0) {
            if (w == 0) {
                const uint* fp = gflags + ((lane & 31) << 4);
                const uint target = (uint)tt;
                while (!__all(load_sc_u32(fp) >= target)) __builtin_amdgcn_s_sleep(1);
            }
            __syncthreads();
        }
        f32x4 acc[2][2] = {};
        if (t > 0) {
            const ushort* hprev = hs + (size_t)(t - 1) * 262144;
            // fragment-ordered staging: chunk c = ks*4+mi; per-lane global gather, linear LDS dest
#pragma unroll
            for (int i = 0; i < 16; ++i) {
                const int c = i * 4 + w;
                const int ks = c >> 2, mi = c & 3;
                gload_lds16_l2(hprev + (size_t)(b0 + mi * 16 + l15) * 512 + ks * 32 + lh * 8,
                               &hp[c * 512]);
            }
            __syncthreads();
#pragma unroll
            for (int ks = 0; ks < 16; ++ks) {
                bf16x8 A0 = *(const bf16x8*)&hp[(ks * 4 + 2 * wr) * 512 + lane * 8];
                bf16x8 A1 = *(const bf16x8*)&hp[(ks * 4 + 2 * wr + 1) * 512 + lane * 8];
                acc[0][0] = __builtin_amdgcn_mfma_f32_16x16x32_bf16(A0, Bfr[0][ks], acc[0][0], 0, 0, 0);
                acc[0][1] = __builtin_amdgcn_mfma_f32_16x16x32_bf16(A0, Bfr[1][ks], acc[0][1], 0, 0, 0);
                acc[1][0] = __builtin_amdgcn_mfma_f32_16x16x32_bf16(A1, Bfr[0][ks], acc[1][0], 0, 0, 0);
                acc[1][1] = __builtin_amdgcn_mfma_f32_16x16x32_bf16(A1, Bfr[1][ks], acc[1][1], 0, 0, 0);
            }
        }
        // exchange gate partials: D reg j, lane -> batch row (2wr+m)*16 + lh*4 + j, h-col l15
#pragma unroll
        for (int m = 0; m < 2; ++m)
#pragma unroll
            for (int gg = 0; gg < 2; ++gg)
#pragma unroll
                for (int j = 0; j < 4; ++j)
                    gbuf[2 * wc + gg][(2 * wr + m) * 16 + lh * 4 + j][l15] = acc[m][gg][j];
        __syncthreads();
        // elementwise LSTM cell
        ushort* hout = hs + (size_t)t * 262144;
#pragma unroll
        for (int i = 0; i < 2; ++i) {
            const int e2 = i * 512 + tid * 2;
            const int b = e2 >> 4, hh = e2 & 15;
            float2 gI = *(const float2*)&gbuf[0][b][hh];
            float2 gF = *(const float2*)&gbuf[1][b][hh];
            float2 gG = *(const float2*)&gbuf[2][b][hh];
            float2 gO = *(const float2*)&gbuf[3][b][hh];
            float i0 = fsig(gI.x + b2f((ushort)(xq[i][0] & 0xffff)));
            float i1 = fsig(gI.y + b2f((ushort)(xq[i][0] >> 16)));
            float f0 = fsig(gF.x + b2f((ushort)(xq[i][1] & 0xffff)));
            float f1 = fsig(gF.y + b2f((ushort)(xq[i][1] >> 16)));
            float g0 = ftanh(gG.x + b2f((ushort)(xq[i][2] & 0xffff)));
            float g1 = ftanh(gG.y + b2f((ushort)(xq[i][2] >> 16)));
            float o0 = fsig(gO.x + b2f((ushort)(xq[i][3] & 0xffff)));
            float o1 = fsig(gO.y + b2f((ushort)(xq[i][3] >> 16)));
            float c0 = f0 * creg[2 * i] + i0 * g0;
            float c1 = f1 * creg[2 * i + 1] + i1 * g1;
            float h0v = o0 * ftanh(c0);
            float h1v = o1 * ftanh(c1);
            creg[2 * i] = c0; creg[2 * i + 1] = c1;
            const size_t ci = (size_t)(b0 + b) * 512 + h0 + hh;
            store_sc_u32((uint*)(hout + ci), (uint)f2b(h0v) | ((uint)f2b(h1v) << 16));
            if (t == 127) {
                *(float2*)&hT[ci] = make_float2(h0v, h1v);
                *(float2*)&cT[ci] = make_float2(c0, c1);
            }
        }
        if (tt < 31) {
            asm volatile("s_waitcnt vmcnt(0)" ::: "memory");  // h write-through complete
            __syncthreads();                                   // whole block done
            if (tid == 0) store_sc_u32(myflag, (uint)(tt + 1));
        }
    }
    // persist c for next chunk
#pragma unroll
    for (int i = 0; i < 2; ++i) {
        const int e2 = i * 512 + tid * 2;
        const size_t ci = (size_t)(b0 + (e2 >> 4)) * 512 + h0 + (e2 & 15);
        *(float2*)&cstate[ci] = make_float2(creg[2 * i], creg[2 * i + 1]);
    }
}

// ---------------- output projection ----------------
__global__ __launch_bounds__(256) void outproj_kernel(
    const ushort* __restrict__ hs, const float* __restrict__ Wout,
    const float* __restrict__ bout, float* __restrict__ out) {
    __shared__ ushort lh[32 * 512];
    const int tid = threadIdx.x;
    const size_t r0 = (size_t)blockIdx.x * 32;
    const uint4* gs = (const uint4*)(hs + r0 * 512);
    uint4* ls = (uint4*)lh;
    for (int i = tid; i < 2048; i += 256) ls[i] = gs[i];
    __syncthreads();
    const int rg = tid & 7, vg = tid >> 3;
    float acc[4][2] = {};
    for (int k8 = 0; k8 < 64; ++k8) {
        float hf[4][8];
#pragma unroll
        for (int rr = 0; rr < 4; ++rr) {
            bf16x8 hv = *(const bf16x8*)&lh[(rg * 4 + rr) * 512 + k8 * 8];
#pragma unroll
            for (int j = 0; j < 8; ++j) hf[rr][j] = b2f((ushort)hv[j]);
        }
#pragma unroll
        for (int vi = 0; vi < 2; ++vi) {
            int v = vg + vi * 32;
            if (v < 37) {
                const float* wp = Wout + (size_t)v * 512 + k8 * 8;
                float4 w0 = *(const float4*)wp;
                float4 w1 = *(const float4*)(wp + 4);
                float wv[8] = {w0.x, w0.y, w0.z, w0.w, w1.x, w1.y, w1.z, w1.w};
#pragma unroll
                for (int rr = 0; rr < 4; ++rr) {
                    float s = 0.f;
#pragma unroll
                    for (int j = 0; j < 8; ++j) s += hf[rr][j] * wv[j];
                    acc[rr][vi] += s;
                }
            }
        }
    }
#pragma unroll
    for (int vi = 0; vi < 2; ++vi) {
        int v = vg + vi * 32;
        if (v < 37) {
#pragma unroll
            for (int rr = 0; rr < 4; ++rr) {
                size_t r = r0 + rg * 4 + rr;
                int t = (int)(r >> 9), b = (int)(r & 511);
                out[((size_t)b * 128 + t) * 37 + v] = acc[rr][vi] + bout[v];
            }
        }
    }
}

extern "C" void kernel_launch(void* const* d_in, const int* in_sizes, int n_in,
                              void* d_out, int out_size, void* d_ws, size_t ws_size,
                              hipStream_t stream) {
    (void)in_sizes; (void)n_in; (void)out_size; (void)ws_size;
    const int* tokens = (const int*)d_in[0];
    const float* emb = (const float*)d_in[1];
    const float* Wih_f[3] = {(const float*)d_in[2], (const float*)d_in[6], (const float*)d_in[10]};
    const float* Whh_f[3] = {(const float*)d_in[3], (const float*)d_in[7], (const float*)d_in[11]};
    const float* bih[3] = {(const float*)d_in[4], (const float*)d_in[8], (const float*)d_in[12]};
    const float* bhh[3] = {(const float*)d_in[5], (const float*)d_in[9], (const float*)d_in[13]};
    const float* Wout = (const float*)d_in[14];
    const float* bout = (const float*)d_in[15];
    float* out = (float*)d_out;

    char* ws = (char*)d_ws;
    size_t off = 0;
    auto take = [&](size_t nb) -> void* {
        void* p = ws + off;
        off = (off + nb + 255) & ~(size_t)255;
        return p;
    };
    ushort* x0 = (ushort*)take((size_t)128 * 512 * 256 * 2);   // 16MB  [S][B][E]
    ushort* hsA = (ushort*)take((size_t)128 * 512 * 512 * 2);  // 64MB  [S][B][H]
    ushort* hsB = (ushort*)take((size_t)128 * 512 * 512 * 2);  // 64MB
    ushort* xpj = (ushort*)take((size_t)32 * 512 * 2048 * 2);  // 64MB  chunk [32][B][4H]
    float* cst = (float*)take((size_t)512 * 512 * 4);          // 1MB
    ushort* wih[3];
    wih[0] = (ushort*)take((size_t)2048 * 256 * 2);
    wih[1] = (ushort*)take((size_t)2048 * 512 * 2);
    wih[2] = (ushort*)take((size_t)2048 * 512 * 2);
    ushort* whh[3];
    for (int l = 0; l < 3; ++l) whh[l] = (ushort*)take((size_t)2048 * 512 * 2);
    uint* barbase = (uint*)take((size_t)12 * 4096 * 4);  // per-launch flag regions

    hipMemsetAsync(barbase, 0, (size_t)12 * 4096 * 4, stream);

    f2b_kernel<<<2048, 256, 0, stream>>>(Wih_f[0], wih[0], 2048 * 256);
    f2b_kernel<<<4096, 256, 0, stream>>>(Wih_f[1], wih[1], 2048 * 512);
    f2b_kernel<<<4096, 256, 0, stream>>>(Wih_f[2], wih[2], 2048 * 512);
    for (int l = 0; l < 3; ++l)
        f2b_kernel<<<4096, 256, 0, stream>>>(Whh_f[l], whh[l], 2048 * 512);

    embed_kernel<<<65536, 256, 0, stream>>>(tokens, emb, x0);

    float* hTbase = out + 2424832;
    float* cTbase = out + 2424832 + 786432;
    const ushort* src = x0;
    ushort* hs_out = hsA;
    for (int l = 0; l < 3; ++l) {
        int K = (l == 0) ? 256 : 512;
        hs_out = (l == 1) ? hsB : hsA;
        for (int ch = 0; ch < 4; ++ch) {
            gemm_bias_kernel<<<2048, 256, 0, stream>>>(
                src + (size_t)ch * 16384 * K, wih[l], bih[l], bhh[l], xpj, 16384, 2048, K);
            lstm_chunk_kernel<<<256, 256, 0, stream>>>(
                xpj, whh[l], hs_out, cst,
                hTbase + (size_t)l * 262144, cTbase + (size_t)l * 262144,
                barbase + (size_t)(l * 4 + ch) * 4096, ch * 32);
        }
        src = hs_out;
    }
    outproj_kernel<<<2048, 256, 0, stream>>>(hs_out, Wout, bout, out);
}

// Round 9
// 2559.008 us; speedup vs baseline: 1.1344x; 1.1344x over previous
//
#include <hip/hip_runtime.h>

typedef __attribute__((ext_vector_type(4))) float f32x4;
typedef __attribute__((ext_vector_type(8))) short bf16x8;

#define DEV __device__ __forceinline__

DEV float b2f(ushort u) { return __uint_as_float(((uint)u) << 16); }
DEV ushort f2b(float f) {
    uint u = __float_as_uint(f);
    return (ushort)((u + 0x7fffu + ((u >> 16) & 1u)) >> 16);  // RNE
}
DEV float fsig(float x) {
    return __builtin_amdgcn_rcpf(1.f + __builtin_amdgcn_exp2f(-1.4426950408889634f * x));
}
DEV float ftanh(float x) {
    return 1.f - 2.f * __builtin_amdgcn_rcpf(__builtin_amdgcn_exp2f(2.885390081777927f * x) + 1.f);
}
DEV void gload_lds16(const void* g, void* l) {
    __builtin_amdgcn_global_load_lds(
        (const __attribute__((address_space(1))) void*)g,
        (__attribute__((address_space(3))) void*)l, 16, 0, 0);
}
// staging load, SC0 only: bypass L1, may hit local (XCD) L2
DEV void gload_lds16_l2(const void* g, void* l) {
    __builtin_amdgcn_global_load_lds(
        (const __attribute__((address_space(1))) void*)g,
        (__attribute__((address_space(3))) void*)l, 16, 0, 1);
}
DEV void store_sc_u32(uint* p, uint v) {
    asm volatile("global_store_dword %0, %1, off sc0 sc1" :: "v"(p), "v"(v) : "memory");
}
DEV uint load_sc_u32(const uint* p) {
    uint v;
    asm volatile("global_load_dword %0, %1, off sc0 sc1\n\ts_waitcnt vmcnt(0)"
                 : "=v"(v) : "v"(p) : "memory");
    return v;
}

// ---------------- f32 -> bf16 weight conversion ----------------
__global__ void f2b_kernel(const float* __restrict__ s, ushort* __restrict__ d, int n) {
    int i = blockIdx.x * 256 + threadIdx.x;
    if (i < n) d[i] = f2b(s[i]);
}

// ---------------- embedding gather -> x0 [S][B][E] bf16 ----------------
__global__ void embed_kernel(const int* __restrict__ tok, const float* __restrict__ emb,
                             ushort* __restrict__ x0) {
    int row = blockIdx.x;
    int t = row >> 9, b = row & 511;
    int tk = tok[b * 128 + t];
    x0[(size_t)row * 256 + threadIdx.x] = f2b(emb[(size_t)tk * 256 + threadIdx.x]);
}

// ---------------- bf16 NT GEMM (m97-style): C[m][n] = A[m][:]·Bw[n][:] + bias ----------------
__global__ __launch_bounds__(256) void gemm_bias_kernel(
    const ushort* __restrict__ A, const ushort* __restrict__ Bw,
    const float* __restrict__ bias0, const float* __restrict__ bias1,
    ushort* __restrict__ C, int M, int N, int K) {
    __shared__ ushort la[128 * 32];
    __shared__ ushort lb[128 * 32];
    const int tid = threadIdx.x;
    const int wave = tid >> 6, lane = tid & 63;
    const int ntn = N >> 7;
    const int tm = blockIdx.x / ntn, tn = blockIdx.x % ntn;
    const int m0 = tm << 7, n0 = tn << 7;
    const int wm = (wave >> 1) * 64, wn = (wave & 1) * 64;
    f32x4 acc[4][4] = {};
    const int nks = K >> 5;
    const int srow = tid >> 2, scol = (tid & 3) * 8;
    for (int ks = 0; ks < nks; ++ks) {
        const int k0 = ks << 5;
#pragma unroll
        for (int r = 0; r < 2; ++r) {
            gload_lds16(A + (size_t)(m0 + r * 64 + srow) * K + k0 + scol, &la[r * 2048 + wave * 512]);
            gload_lds16(Bw + (size_t)(n0 + r * 64 + srow) * K + k0 + scol, &lb[r * 2048 + wave * 512]);
        }
        __syncthreads();
        bf16x8 af[4], bfr[4];
#pragma unroll
        for (int i = 0; i < 4; ++i)
            af[i] = *(const bf16x8*)&la[(wm + i * 16 + (lane & 15)) * 32 + (lane >> 4) * 8];
#pragma unroll
        for (int i = 0; i < 4; ++i)
            bfr[i] = *(const bf16x8*)&lb[(wn + i * 16 + (lane & 15)) * 32 + (lane >> 4) * 8];
#pragma unroll
        for (int mi = 0; mi < 4; ++mi)
#pragma unroll
            for (int ni = 0; ni < 4; ++ni)
                acc[mi][ni] = __builtin_amdgcn_mfma_f32_16x16x32_bf16(af[mi], bfr[ni], acc[mi][ni], 0, 0, 0);
        __syncthreads();
    }
#pragma unroll
    for (int mi = 0; mi < 4; ++mi) {
        int row = m0 + wm + mi * 16 + ((lane >> 4) << 2);
#pragma unroll
        for (int j = 0; j < 4; ++j) {
#pragma unroll
            for (int ni = 0; ni < 4; ++ni) {
                int col = n0 + wn + ni * 16 + (lane & 15);
                C[(size_t)(row + j) * N + col] = f2b(acc[mi][ni][j] + bias0[col] + bias1[col]);
            }
        }
    }
}

// ---------------- persistent LSTM chunk: 32 timesteps, device-scope flag barrier ----------------
// grid 256 = 8 batch-groups (grp = bid&7, XCD-local staging) x 32 h-slices.
// R6 structure; single change: xq (xpj) loads are software-pipelined one step ahead so the
// flag poll's vmcnt(0) never drains HBM-latency xpj loads (they drain under the staging barrier).
__global__ __launch_bounds__(256) void lstm_chunk_kernel(
    const ushort* __restrict__ xpj,   // [32][512][2048] bf16 (x-projections incl. biases)
    const ushort* __restrict__ Whh,   // [2048][512] bf16
    ushort* __restrict__ hs,          // [128][512][512] bf16 (layer history)
    float* __restrict__ cstate,       // [512][512] f32
    float* __restrict__ hT, float* __restrict__ cT,
    uint* __restrict__ bar,           // this launch: 8 groups x 32 slices x 16 uints (zeroed)
    int t0) {
    __shared__ ushort hp[64 * 512];    // 64KB staged hprev tile (16B-chunk XOR swizzled rows)
    __shared__ float gbuf[4][64][20];
    const int tid = threadIdx.x;
    const int wave = tid >> 6, lane = tid & 63;
    const int grp = blockIdx.x & 7;   // XCD-local group
    const int hsl = blockIdx.x >> 3;  // h-slice 0..31
    const int b0 = grp << 6, h0 = hsl << 4;
    uint* gflags = bar + grp * 512;
    uint* myflag = gflags + hsl * 16;

    // one-time acquire: drop stale L2 lines from previous dispatches/replays
    __threadfence();

    // Whh fragments for this wave's gate: 16 K-steps x bf16x8 (64 VGPRs)
    bf16x8 Bfr[16];
    const ushort* wb = Whh + ((size_t)(wave * 512 + h0 + (lane & 15))) * 512 + (lane >> 4) * 8;
#pragma unroll
    for (int ks = 0; ks < 16; ++ks) Bfr[ks] = *(const bf16x8*)(wb + ks * 32);

    // c-state registers (2 adjacent h per slot pair)
    float creg[4];
#pragma unroll
    for (int i = 0; i < 2; ++i) {
        const int e2 = i * 512 + tid * 2;
        const size_t ci = (size_t)(b0 + (e2 >> 4)) * 512 + h0 + (e2 & 15);
        if (t0 > 0) {
            float2 cv = *(const float2*)&cstate[ci];
            creg[2 * i] = cv.x; creg[2 * i + 1] = cv.y;
        } else {
            creg[2 * i] = 0.f; creg[2 * i + 1] = 0.f;
        }
    }

    // prologue: xq for local step 0
    uint xqc[8];
#pragma unroll
    for (int i = 0; i < 2; ++i) {
        const int e2 = i * 512 + tid * 2;
        const uint* xb = (const uint*)(xpj + (size_t)(b0 + (e2 >> 4)) * 2048 + h0 + (e2 & 15));
        xqc[i * 4 + 0] = xb[0]; xqc[i * 4 + 1] = xb[256];
        xqc[i * 4 + 2] = xb[512]; xqc[i * 4 + 3] = xb[768];
    }

    for (int tt = 0; tt < 32; ++tt) {
        const int t = t0 + tt;
        // wait for all 32 slice-blocks of this group to have produced h[t-1]
        if (tt > 0) {
            if (wave == 0) {
                const uint* fp = gflags + ((lane & 31) << 4);
                const uint target = (uint)tt;
                while (!__all(load_sc_u32(fp) >= target)) __builtin_amdgcn_s_sleep(1);
            }
            __syncthreads();
        }
        f32x4 acc[4] = {};
        uint xqn[8];
        if (t > 0) {
            const ushort* hprev = hs + (size_t)(t - 1) * 262144;
            // stage hprev rows (1KB contiguous per instruction, source-XOR-swizzled)
#pragma unroll
            for (int rr = 0; rr < 16; ++rr) {
                const int row = rr * 4 + wave;
                gload_lds16_l2(hprev + (size_t)(b0 + row) * 512 + ((lane ^ (row & 7)) * 8),
                               &hp[row * 512]);
            }
            // prefetch NEXT step's xq — drains together with staging under the barrier below
            if (tt < 31) {
                const ushort* xt = xpj + (size_t)(tt + 1) * 1048576;
#pragma unroll
                for (int i = 0; i < 2; ++i) {
                    const int e2 = i * 512 + tid * 2;
                    const uint* xb = (const uint*)(xt + (size_t)(b0 + (e2 >> 4)) * 2048 + h0 + (e2 & 15));
                    xqn[i * 4 + 0] = xb[0]; xqn[i * 4 + 1] = xb[256];
                    xqn[i * 4 + 2] = xb[512]; xqn[i * 4 + 3] = xb[768];
                }
            }
            __syncthreads();
#pragma unroll
            for (int ks = 0; ks < 16; ++ks) {
#pragma unroll
                for (int mi = 0; mi < 4; ++mi) {
                    const int row = mi * 16 + (lane & 15);
                    const int c16 = (ks * 4 + (lane >> 4)) ^ (row & 7);
                    bf16x8 af = *(const bf16x8*)&hp[row * 512 + c16 * 8];
                    acc[mi] = __builtin_amdgcn_mfma_f32_16x16x32_bf16(af, Bfr[ks], acc[mi], 0, 0, 0);
                }
            }
        } else if (tt < 31) {
            // t==0: no staging; still prefetch next xq
            const ushort* xt = xpj + (size_t)(tt + 1) * 1048576;
#pragma unroll
            for (int i = 0; i < 2; ++i) {
                const int e2 = i * 512 + tid * 2;
                const uint* xb = (const uint*)(xt + (size_t)(b0 + (e2 >> 4)) * 2048 + h0 + (e2 & 15));
                xqn[i * 4 + 0] = xb[0]; xqn[i * 4 + 1] = xb[256];
                xqn[i * 4 + 2] = xb[512]; xqn[i * 4 + 3] = xb[768];
            }
        }
#pragma unroll
        for (int mi = 0; mi < 4; ++mi) {
            const int rloc = mi * 16 + ((lane >> 4) << 2);
#pragma unroll
            for (int j = 0; j < 4; ++j) gbuf[wave][rloc + j][lane & 15] = acc[mi][j];
        }
        __syncthreads();
        // elementwise LSTM cell (uses current-step xqc)
        ushort* hout = hs + (size_t)t * 262144;
#pragma unroll
        for (int i = 0; i < 2; ++i) {
            const int e2 = i * 512 + tid * 2;
            const int b = e2 >> 4, hh = e2 & 15;
            float2 gI = *(const float2*)&gbuf[0][b][hh];
            float2 gF = *(const float2*)&gbuf[1][b][hh];
            float2 gG = *(const float2*)&gbuf[2][b][hh];
            float2 gO = *(const float2*)&gbuf[3][b][hh];
            float i0 = fsig(gI.x + b2f((ushort)(xqc[i * 4 + 0] & 0xffff)));
            float i1 = fsig(gI.y + b2f((ushort)(xqc[i * 4 + 0] >> 16)));
            float f0 = fsig(gF.x + b2f((ushort)(xqc[i * 4 + 1] & 0xffff)));
            float f1 = fsig(gF.y + b2f((ushort)(xqc[i * 4 + 1] >> 16)));
            float g0 = ftanh(gG.x + b2f((ushort)(xqc[i * 4 + 2] & 0xffff)));
            float g1 = ftanh(gG.y + b2f((ushort)(xqc[i * 4 + 2] >> 16)));
            float o0 = fsig(gO.x + b2f((ushort)(xqc[i * 4 + 3] & 0xffff)));
            float o1 = fsig(gO.y + b2f((ushort)(xqc[i * 4 + 3] >> 16)));
            float c0 = f0 * creg[2 * i] + i0 * g0;
            float c1 = f1 * creg[2 * i + 1] + i1 * g1;
            float h0v = o0 * ftanh(c0);
            float h1v = o1 * ftanh(c1);
            creg[2 * i] = c0; creg[2 * i + 1] = c1;
            const size_t ci = (size_t)(b0 + b) * 512 + h0 + hh;
            store_sc_u32((uint*)(hout + ci), (uint)f2b(h0v) | ((uint)f2b(h1v) << 16));
            if (t == 127) {
                *(float2*)&hT[ci] = make_float2(h0v, h1v);
                *(float2*)&cT[ci] = make_float2(c0, c1);
            }
        }
        // rotate pipelined xq
        if (tt < 31) {
#pragma unroll
            for (int k = 0; k < 8; ++k) xqc[k] = xqn[k];
        }
        if (tt < 31) {
            asm volatile("s_waitcnt vmcnt(0)" ::: "memory");  // h write-through complete
            __syncthreads();                                   // whole block done
            if (tid == 0) store_sc_u32(myflag, (uint)(tt + 1));
        }
    }
    // persist c for next chunk
#pragma unroll
    for (int i = 0; i < 2; ++i) {
        const int e2 = i * 512 + tid * 2;
        const size_t ci = (size_t)(b0 + (e2 >> 4)) * 512 + h0 + (e2 & 15);
        *(float2*)&cstate[ci] = make_float2(creg[2 * i], creg[2 * i + 1]);
    }
}

// ---------------- output projection ----------------
__global__ __launch_bounds__(256) void outproj_kernel(
    const ushort* __restrict__ hs, const float* __restrict__ Wout,
    const float* __restrict__ bout, float* __restrict__ out) {
    __shared__ ushort lh[32 * 512];
    const int tid = threadIdx.x;
    const size_t r0 = (size_t)blockIdx.x * 32;
    const uint4* gs = (const uint4*)(hs + r0 * 512);
    uint4* ls = (uint4*)lh;
    for (int i = tid; i < 2048; i += 256) ls[i] = gs[i];
    __syncthreads();
    const int rg = tid & 7, vg = tid >> 3;
    float acc[4][2] = {};
    for (int k8 = 0; k8 < 64; ++k8) {
        float hf[4][8];
#pragma unroll
        for (int rr = 0; rr < 4; ++rr) {
            bf16x8 hv = *(const bf16x8*)&lh[(rg * 4 + rr) * 512 + k8 * 8];
#pragma unroll
            for (int j = 0; j < 8; ++j) hf[rr][j] = b2f((ushort)hv[j]);
        }
#pragma unroll
        for (int vi = 0; vi < 2; ++vi) {
            int v = vg + vi * 32;
            if (v < 37) {
                const float* wp = Wout + (size_t)v * 512 + k8 * 8;
                float4 w0 = *(const float4*)wp;
                float4 w1 = *(const float4*)(wp + 4);
                float wv[8] = {w0.x, w0.y, w0.z, w0.w, w1.x, w1.y, w1.z, w1.w};
#pragma unroll
                for (int rr = 0; rr < 4; ++rr) {
                    float s = 0.f;
#pragma unroll
                    for (int j = 0; j < 8; ++j) s += hf[rr][j] * wv[j];
                    acc[rr][vi] += s;
                }
            }
        }
    }
#pragma unroll
    for (int vi = 0; vi < 2; ++vi) {
        int v = vg + vi * 32;
        if (v < 37) {
#pragma unroll
            for (int rr = 0; rr < 4; ++rr) {
                size_t r = r0 + rg * 4 + rr;
                int t = (int)(r >> 9), b = (int)(r & 511);
                out[((size_t)b * 128 + t) * 37 + v] = acc[rr][vi] + bout[v];
            }
        }
    }
}

extern "C" void kernel_launch(void* const* d_in, const int* in_sizes, int n_in,
                              void* d_out, int out_size, void* d_ws, size_t ws_size,
                              hipStream_t stream) {
    (void)in_sizes; (void)n_in; (void)out_size; (void)ws_size;
    const int* tokens = (const int*)d_in[0];
    const float* emb = (const float*)d_in[1];
    const float* Wih_f[3] = {(const float*)d_in[2], (const float*)d_in[6], (const float*)d_in[10]};
    const float* Whh_f[3] = {(const float*)d_in[3], (const float*)d_in[7], (const float*)d_in[11]};
    const float* bih[3] = {(const float*)d_in[4], (const float*)d_in[8], (const float*)d_in[12]};
    const float* bhh[3] = {(const float*)d_in[5], (const float*)d_in[9], (const float*)d_in[13]};
    const float* Wout = (const float*)d_in[14];
    const float* bout = (const float*)d_in[15];
    float* out = (float*)d_out;

    char* ws = (char*)d_ws;
    size_t off = 0;
    auto take = [&](size_t nb) -> void* {
        void* p = ws + off;
        off = (off + nb + 255) & ~(size_t)255;
        return p;
    };
    ushort* x0 = (ushort*)take((size_t)128 * 512 * 256 * 2);   // 16MB  [S][B][E]
    ushort* hsA = (ushort*)take((size_t)128 * 512 * 512 * 2);  // 64MB  [S][B][H]
    ushort* hsB = (ushort*)take((size_t)128 * 512 * 512 * 2);  // 64MB
    ushort* xpj = (ushort*)take((size_t)32 * 512 * 2048 * 2);  // 64MB  chunk [32][B][4H]
    float* cst = (float*)take((size_t)512 * 512 * 4);          // 1MB
    ushort* wih[3];
    wih[0] = (ushort*)take((size_t)2048 * 256 * 2);
    wih[1] = (ushort*)take((size_t)2048 * 512 * 2);
    wih[2] = (ushort*)take((size_t)2048 * 512 * 2);
    ushort* whh[3];
    for (int l = 0; l < 3; ++l) whh[l] = (ushort*)take((size_t)2048 * 512 * 2);
    uint* barbase = (uint*)take((size_t)12 * 4096 * 4);  // per-launch flag regions

    hipMemsetAsync(barbase, 0, (size_t)12 * 4096 * 4, stream);

    f2b_kernel<<<2048, 256, 0, stream>>>(Wih_f[0], wih[0], 2048 * 256);
    f2b_kernel<<<4096, 256, 0, stream>>>(Wih_f[1], wih[1], 2048 * 512);
    f2b_kernel<<<4096, 256, 0, stream>>>(Wih_f[2], wih[2], 2048 * 512);
    for (int l = 0; l < 3; ++l)
        f2b_kernel<<<4096, 256, 0, stream>>>(Whh_f[l], whh[l], 2048 * 512);

    embed_kernel<<<65536, 256, 0, stream>>>(tokens, emb, x0);

    float* hTbase = out + 2424832;
    float* cTbase = out + 2424832 + 786432;
    const ushort* src = x0;
    ushort* hs_out = hsA;
    for (int l = 0; l < 3; ++l) {
        int K = (l == 0) ? 256 : 512;
        hs_out = (l == 1) ? hsB : hsA;
        for (int ch = 0; ch < 4; ++ch) {
            gemm_bias_kernel<<<2048, 256, 0, stream>>>(
                src + (size_t)ch * 16384 * K, wih[l], bih[l], bhh[l], xpj, 16384, 2048, K);
            lstm_chunk_kernel<<<256, 256, 0, stream>>>(
                xpj, whh[l], hs_out, cst,
                hTbase + (size_t)l * 262144, cTbase + (size_t)l * 262144,
                barbase + (size_t)(l * 4 + ch) * 4096, ch * 32);
        }
        src = hs_out;
    }
    outproj_kernel<<<2048, 256, 0, stream>>>(hs_out, Wout, bout, out);
}